// Round 8
// baseline (7230.882 us; speedup 1.0000x reference)
//
#include <hip/hip_runtime.h>
#include <cstdint>
#include <cstddef>

#define T_OBS_C 64
#define T_UNOBS_C 32
#define BATCH_C 4096
#define HID_C 256

typedef short v8s __attribute__((ext_vector_type(8)));
typedef float v4f __attribute__((ext_vector_type(4)));
typedef unsigned short u16x8 __attribute__((ext_vector_type(8)));

__device__ __forceinline__ float bf2f(unsigned short u) {
  union { unsigned int i; float f; } v; v.i = ((unsigned int)u) << 16; return v.f;
}
__device__ __forceinline__ unsigned short f2bf(float f) {
  union { float f; unsigned int i; } v; v.f = f;
  unsigned int r = (v.i + 0x7FFFu + ((v.i >> 16) & 1u)) >> 16;
  return (unsigned short)r;
}

// ---------------------------------------------------------------------------
// prep (unchanged, verified):
//   Wc = wi @ stem_w2  -> hi/lo bf16 ; wi, wh -> hi/lo bf16
//   bc_obs[n] = sum_j wi[n][j]*b2[j] + bi[n]
// ---------------------------------------------------------------------------
__global__ void prep_kernel(const float* __restrict__ wi,
                            const float* __restrict__ w2,
                            const float* __restrict__ b2,
                            const float* __restrict__ bi,
                            unsigned short* __restrict__ wi_hi,
                            unsigned short* __restrict__ wi_lo,
                            const float* __restrict__ wh,
                            unsigned short* __restrict__ wh_hi,
                            unsigned short* __restrict__ wh_lo,
                            unsigned short* __restrict__ wc_hi,
                            unsigned short* __restrict__ wc_lo,
                            float* __restrict__ bc_obs) {
  const int n = blockIdx.x;     // 0..767
  const int k = threadIdx.x;    // 0..255
  const int idx = n * 256 + k;

  float wv = wi[idx];
  unsigned short h1 = f2bf(wv);
  wi_hi[idx] = h1; wi_lo[idx] = f2bf(wv - bf2f(h1));

  float hv = wh[idx];
  unsigned short h2 = f2bf(hv);
  wh_hi[idx] = h2; wh_lo[idx] = f2bf(hv - bf2f(h2));

  float acc = 0.f;
  for (int j = 0; j < 256; ++j)
    acc += wi[n * 256 + j] * w2[j * 256 + k];
  unsigned short h3 = f2bf(acc);
  wc_hi[idx] = h3; wc_lo[idx] = f2bf(acc - bf2f(h3));

  if (k == 0) {
    float b = 0.f;
    for (int j = 0; j < 256; ++j) b += wi[n * 256 + j] * b2[j];
    bc_obs[n] = b + bi[n];
  }
}

// ---------------------------------------------------------------------------
// Weight-stationary persistent RNN, v3: per-WAVE lock-free pipeline.
// 256 blocks x 8 waves = 2048 independent 32-row x 16-col slab processors.
// Weights (144KB) + stem weights live in block-shared LDS (read-only after
// init). NO intra-block sync in the step loop: each wave signals its slab
// counter (release) after writing h, and polls (relaxed + final acquire)
// before reading h(t). 16 cg-waves share a slab counter; drift <= 1 step
// (same WAR-safety argument as the round-6 block barrier, per-wave).
// h layout [cg][4096 rows][16 cols]: each wave's slice is private 1KB
// contiguous -> no cross-block false sharing on 64B lines.
// ---------------------------------------------------------------------------
__global__ __launch_bounds__(512, 2)
void rnn_wave(const float* __restrict__ x_obs,
              const float* __restrict__ t_obs,
              const float* __restrict__ w1,
              const float* __restrict__ b1,
              const unsigned short* __restrict__ wc_hi, const unsigned short* __restrict__ wc_lo,
              const unsigned short* __restrict__ wi_hi, const unsigned short* __restrict__ wi_lo,
              const unsigned short* __restrict__ wh_hi, const unsigned short* __restrict__ wh_lo,
              const float* __restrict__ bc_obs,
              const float* __restrict__ bi,
              const float* __restrict__ bh,
              const float* __restrict__ head_w,
              const float* __restrict__ head_b,
              unsigned short* h_hi0, unsigned short* h_lo0,
              unsigned short* h_hi1, unsigned short* h_lo1,
              unsigned int* cnt,
              float* out_x,
              float* out_z) {
  // [(mat*3+g)*2+hl][16 rows][32 c16-chunks swizzled] = 18*4096 ushorts = 144KB
  __shared__ unsigned short wlds[73728];
  __shared__ float w1t[1280];   // [5][256] transposed stem weights
  __shared__ float b1s[256];

  const int tid = threadIdx.x;
  const int bid = blockIdx.x;
  const int jj  = bid & 15;
  const int cg  = bid >> 4;
  const int rr  = ((jj & 7) << 1) | (jj >> 3);   // same-rr blocks share XCD (perf)
  const int m0  = rr << 8;                       // 256 rows per block
  const int c0  = cg << 4;                       // 16 h-cols per col-group

  // ---- one-time: weight slices + stem weights into LDS ----
  {
    const unsigned short* srcs[6] = {wc_hi, wc_lo, wi_hi, wi_lo, wh_hi, wh_lo};
    for (int id = tid; id < 9216; id += 512) {
      const int sub = id >> 9;                 // 0..17 == (mat*3+g)*2+hl
      const int mat = sub / 6;
      const int g   = (sub >> 1) % 3;
      const int hl  = sub & 1;
      const int within = id & 511;
      const int row = within >> 5;             // 0..15
      const int c16 = within & 31;
      const unsigned short* s = srcs[mat * 2 + hl] +
          (((size_t)(g * 256 + c0 + row)) << 8) + (c16 << 3);
      u16x8 v = *(const u16x8*)s;
      *(u16x8*)(wlds + (sub << 12) + (row << 8) + ((c16 ^ row) << 3)) = v;
    }
    for (int i = tid; i < 1280; i += 512) {
      const int k = i / 5, j = i - k * 5;
      w1t[j * 256 + k] = w1[i];
    }
    if (tid < 256) b1s[tid] = b1[tid];
  }

  const int wave = tid >> 6;      // 0..7: independent 32-row slab
  const int lane = tid & 63;
  const int quad = lane >> 4;
  const int l16  = lane & 15;
  const int jc   = c0 + l16;      // this thread's h-col

  float xb_o[3], xb_a[3], hb_[3], hwv[4];
  #pragma unroll
  for (int g = 0; g < 3; ++g) {
    xb_o[g] = bc_obs[g * 256 + jc];
    xb_a[g] = bi[g * 256 + jc];
    hb_[g]  = bh[g * 256 + jc];
  }
  #pragma unroll
  for (int d = 0; d < 4; ++d) hwv[d] = head_b[0] * 0.f + head_w[d * 256 + jc];

  const int rowL0 = wave * 32 + l16;             // local rows (A-frag)
  const int rowL1 = rowL0 + 16;
  const size_t rb0 = (size_t)(m0 + rowL0) << 4;  // [cg][row][16] row base
  const size_t rb1 = (size_t)(m0 + rowL1) << 4;
  const size_t xr0 = (size_t)(m0 + rowL0);       // x_obs row index
  const size_t xr1 = (size_t)(m0 + rowL1);

  unsigned int* cslab = cnt + ((rr * 8 + wave) << 4);   // 64B-padded counter

  // wave-scope signal/wait (agent scope; wave-wide vmcnt drain before signal)
  auto wave_signal = [&]() {
    asm volatile("s_waitcnt vmcnt(0)" ::: "memory");
    if (lane == 0)
      __hip_atomic_fetch_add(cslab, 1u, __ATOMIC_RELEASE, __HIP_MEMORY_SCOPE_AGENT);
  };
  auto wave_wait = [&](unsigned int tgt) {
    while (__hip_atomic_load(cslab, __ATOMIC_RELAXED, __HIP_MEMORY_SCOPE_AGENT) < tgt)
      __builtin_amdgcn_s_sleep(2);
    (void)__hip_atomic_load(cslab, __ATOMIC_ACQUIRE, __HIP_MEMORY_SCOPE_AGENT);
  };

  __syncthreads();   // LDS weights ready (only block-wide sync in the kernel)

  // x-state for the next obs step (registers)
  float4 xv0, xv1; float td0 = 0.f, td1 = 0.f;
  auto load_x = [&](int tt) {
    const size_t xo0 = (size_t)tt * BATCH_C + xr0;
    const size_t xo1 = (size_t)tt * BATCH_C + xr1;
    xv0 = *(const float4*)(x_obs + xo0 * 4);
    xv1 = *(const float4*)(x_obs + xo1 * 4);
    if (tt > 0) {
      td0 = t_obs[xo0] - t_obs[xo0 - BATCH_C];
      td1 = t_obs[xo1] - t_obs[xo1 - BATCH_C];
    } else { td0 = 0.f; td1 = 0.f; }
  };

  // pre-computed obs x-path: stem fragments on the fly + MFMA vs LDS Wc slice
  v4f aXp[2][3];
  auto xpath_pre = [&]() {
    #pragma unroll
    for (int mt = 0; mt < 2; ++mt)
      #pragma unroll
      for (int g = 0; g < 3; ++g)
        aXp[mt][g] = (v4f){0.f, 0.f, 0.f, 0.f};
    #pragma unroll
    for (int kc = 0; kc < 8; ++kc) {
      v8s s0h, s0l, s1h, s1l;
      #pragma unroll
      for (int j = 0; j < 8; ++j) {
        const int k = kc * 32 + quad * 8 + j;
        const float wA = w1t[k], wB = w1t[256 + k], wC = w1t[512 + k],
                    wD = w1t[768 + k], wE = w1t[1024 + k];
        const float bb = b1s[k];
        float p0 = xv0.x * wA + xv0.y * wB + xv0.z * wC + xv0.w * wD + td0 * wE + bb;
        float a0 = (p0 > 0.f) ? p0 : 0.01f * p0;    // leaky_relu 0.01
        unsigned short h0 = f2bf(a0);
        s0h[j] = h0; s0l[j] = f2bf(a0 - bf2f(h0));
        float p1 = xv1.x * wA + xv1.y * wB + xv1.z * wC + xv1.w * wD + td1 * wE + bb;
        float a1 = (p1 > 0.f) ? p1 : 0.01f * p1;
        unsigned short h1 = f2bf(a1);
        s1h[j] = h1; s1l[j] = f2bf(a1 - bf2f(h1));
      }
      const int lrow = (l16 << 8) + ((((kc * 4 + quad) ^ l16)) << 3);
      #pragma unroll
      for (int g = 0; g < 3; ++g) {
        const v8s bxh = *(const v8s*)(wlds + ((g * 2 + 0) << 12) + lrow);  // wc hi
        const v8s bxl = *(const v8s*)(wlds + ((g * 2 + 1) << 12) + lrow);  // wc lo
        aXp[0][g] = __builtin_amdgcn_mfma_f32_16x16x32_bf16(s0h, bxh, aXp[0][g], 0, 0, 0);
        aXp[0][g] = __builtin_amdgcn_mfma_f32_16x16x32_bf16(s0l, bxh, aXp[0][g], 0, 0, 0);
        aXp[0][g] = __builtin_amdgcn_mfma_f32_16x16x32_bf16(s0h, bxl, aXp[0][g], 0, 0, 0);
        aXp[1][g] = __builtin_amdgcn_mfma_f32_16x16x32_bf16(s1h, bxh, aXp[1][g], 0, 0, 0);
        aXp[1][g] = __builtin_amdgcn_mfma_f32_16x16x32_bf16(s1l, bxh, aXp[1][g], 0, 0, 0);
        aXp[1][g] = __builtin_amdgcn_mfma_f32_16x16x32_bf16(s1h, bxl, aXp[1][g], 0, 0, 0);
      }
    }
  };

  load_x(0);
  xpath_pre();        // step 0's x-path (h0 from memset, stream-ordered)

  #pragma unroll 1
  for (int step = 0; step < T_OBS_C + T_UNOBS_C - 1; ++step) {
    const bool obs = (step < T_OBS_C);
    const unsigned short* hih = (step & 1) ? h_hi1 : h_hi0;
    const unsigned short* hil = (step & 1) ? h_lo1 : h_lo0;
    unsigned short* hoh = (step & 1) ? h_hi0 : h_hi1;
    unsigned short* hol = (step & 1) ? h_lo0 : h_lo1;
    const int zi = (step == T_OBS_C - 1) ? 0
                   : (step >= T_OBS_C ? step - (T_OBS_C - 1) : -1);

    v4f aX[2][3], aH[2][3];
    #pragma unroll
    for (int mt = 0; mt < 2; ++mt)
      #pragma unroll
      for (int g = 0; g < 3; ++g) {
        aX[mt][g] = obs ? aXp[mt][g] : (v4f){0.f, 0.f, 0.f, 0.f};
        aH[mt][g] = (v4f){0.f, 0.f, 0.f, 0.f};
      }

    if (step > 0) wave_wait((unsigned int)step << 4);   // h(step) ready

    // A-frag loads from [cg][row][16] layout: ko=kc*32+quad*8 ->
    // cgk = kc*2 + (quad>>1), kw = (quad&1)*8
    #pragma unroll
    for (int kc = 0; kc < 8; ++kc) {
      const size_t co = ((size_t)(kc * 2 + (quad >> 1)) << 16) + ((quad & 1) << 3);
      const v8s ah0h = *(const v8s*)(hih + co + rb0);
      const v8s ah0l = *(const v8s*)(hil + co + rb0);
      const v8s ah1h = *(const v8s*)(hih + co + rb1);
      const v8s ah1l = *(const v8s*)(hil + co + rb1);
      const int lrow = (l16 << 8) + ((((kc * 4 + quad) ^ l16)) << 3);
      if (!obs) {
        #pragma unroll
        for (int g = 0; g < 3; ++g) {
          const v8s bxh = *(const v8s*)(wlds + (((3 + g) * 2 + 0) << 12) + lrow);  // wi
          const v8s bxl = *(const v8s*)(wlds + (((3 + g) * 2 + 1) << 12) + lrow);
          aX[0][g] = __builtin_amdgcn_mfma_f32_16x16x32_bf16(ah0h, bxh, aX[0][g], 0, 0, 0);
          aX[0][g] = __builtin_amdgcn_mfma_f32_16x16x32_bf16(ah0l, bxh, aX[0][g], 0, 0, 0);
          aX[0][g] = __builtin_amdgcn_mfma_f32_16x16x32_bf16(ah0h, bxl, aX[0][g], 0, 0, 0);
          aX[1][g] = __builtin_amdgcn_mfma_f32_16x16x32_bf16(ah1h, bxh, aX[1][g], 0, 0, 0);
          aX[1][g] = __builtin_amdgcn_mfma_f32_16x16x32_bf16(ah1l, bxh, aX[1][g], 0, 0, 0);
          aX[1][g] = __builtin_amdgcn_mfma_f32_16x16x32_bf16(ah1h, bxl, aX[1][g], 0, 0, 0);
        }
      }
      #pragma unroll
      for (int g = 0; g < 3; ++g) {
        const v8s bhh = *(const v8s*)(wlds + (((6 + g) * 2 + 0) << 12) + lrow);    // wh
        const v8s bhl = *(const v8s*)(wlds + (((6 + g) * 2 + 1) << 12) + lrow);
        aH[0][g] = __builtin_amdgcn_mfma_f32_16x16x32_bf16(ah0h, bhh, aH[0][g], 0, 0, 0);
        aH[0][g] = __builtin_amdgcn_mfma_f32_16x16x32_bf16(ah0l, bhh, aH[0][g], 0, 0, 0);
        aH[0][g] = __builtin_amdgcn_mfma_f32_16x16x32_bf16(ah0h, bhl, aH[0][g], 0, 0, 0);
        aH[1][g] = __builtin_amdgcn_mfma_f32_16x16x32_bf16(ah1h, bhh, aH[1][g], 0, 0, 0);
        aH[1][g] = __builtin_amdgcn_mfma_f32_16x16x32_bf16(ah1l, bhh, aH[1][g], 0, 0, 0);
        aH[1][g] = __builtin_amdgcn_mfma_f32_16x16x32_bf16(ah1h, bhl, aH[1][g], 0, 0, 0);
      }
    }

    // ---- gate epilogue: thread owns col jc, rows wave*32 + mt*16 + quad*4+r ----
    #pragma unroll
    for (int mt = 0; mt < 2; ++mt) {
      #pragma unroll
      for (int r = 0; r < 4; ++r) {
        const int grow = m0 + wave * 32 + mt * 16 + quad * 4 + r;
        const size_t hoff = ((size_t)cg << 16) + ((size_t)grow << 4) + l16;
        const float xbr = obs ? xb_o[0] : xb_a[0];
        const float xbz = obs ? xb_o[1] : xb_a[1];
        const float xbn = obs ? xb_o[2] : xb_a[2];
        float gr = aX[mt][0][r] + xbr + aH[mt][0][r] + hb_[0];
        float gz = aX[mt][1][r] + xbz + aH[mt][1][r] + hb_[1];
        float nx = aX[mt][2][r] + xbn;
        float nh = aH[mt][2][r] + hb_[2];
        float rr2 = 1.f / (1.f + expf(-gr));
        float uu = 1.f / (1.f + expf(-gz));
        float nn = tanhf(nx + rr2 * nh);
        float hold = bf2f(hih[hoff]) + bf2f(hil[hoff]);
        float hnew = (1.f - uu) * nn + uu * hold;
        unsigned short hi = f2bf(hnew);
        hoh[hoff] = hi;
        hol[hoff] = f2bf(hnew - bf2f(hi));
        if (zi >= 0) {
          out_z[((size_t)zi << 20) + ((size_t)grow << 8) + jc] = hnew;
          #pragma unroll
          for (int d = 0; d < 4; ++d) {
            float pd = hnew * hwv[d];
            pd += __shfl_xor(pd, 1);
            pd += __shfl_xor(pd, 2);
            pd += __shfl_xor(pd, 4);
            pd += __shfl_xor(pd, 8);
            if (l16 == 0) {
              if (cg == 0) pd += head_b[d];
              atomicAdd(out_x + ((((size_t)zi << 12) + grow) << 2) + d, pd);
            }
          }
        }
      }
    }

    if (step < T_OBS_C + T_UNOBS_C - 2) wave_signal();   // h(step+1) published

    if (step + 1 < T_OBS_C) {     // next obs x-path in the signal/poll shadow
      load_x(step + 1);
      xpath_pre();
    }
  }
}

// ---------------------------------------------------------------------------
extern "C" void kernel_launch(void* const* d_in, const int* in_sizes, int n_in,
                              void* d_out, int out_size, void* d_ws, size_t ws_size,
                              hipStream_t stream) {
  const float* x_obs = (const float*)d_in[0];
  const float* t_obs = (const float*)d_in[1];
  // d_in[2] = t_unobs: only its length (32) matters
  const float* w1 = (const float*)d_in[3];
  const float* b1 = (const float*)d_in[4];
  const float* w2 = (const float*)d_in[5];
  const float* b2 = (const float*)d_in[6];
  const float* wi = (const float*)d_in[7];
  const float* wh = (const float*)d_in[8];
  const float* bi = (const float*)d_in[9];
  const float* bh = (const float*)d_in[10];
  const float* hw = (const float*)d_in[11];
  const float* hb = (const float*)d_in[12];

  float* out_x = (float*)d_out;                                  // [32,4096,4]
  float* out_z = out_x + (size_t)T_UNOBS_C * BATCH_C * 4;        // [32,4096,256]

  // workspace: weights 2.36MB + h ping-pong 8MB + counters (~11 MB)
  unsigned short* p = (unsigned short*)d_ws;
  unsigned short* wi_hi = p; p += 768 * 256;
  unsigned short* wi_lo = p; p += 768 * 256;
  unsigned short* wh_hi = p; p += 768 * 256;
  unsigned short* wh_lo = p; p += 768 * 256;
  unsigned short* wc_hi = p; p += 768 * 256;
  unsigned short* wc_lo = p; p += 768 * 256;
  unsigned short* h_hi0 = p; p += (size_t)1 << 20;
  unsigned short* h_lo0 = p; p += (size_t)1 << 20;
  unsigned short* h_hi1 = p; p += (size_t)1 << 20;
  unsigned short* h_lo1 = p; p += (size_t)1 << 20;
  float* bc_obs = (float*)p; p += 768 * 2;
  unsigned int* cnt = (unsigned int*)p;            // 128 slabs x 16 u32 (64B pad)

  // h0 = 0 (h_hi0 + h_lo0 contiguous), counters = 0, out_x = 0 (atomic target)
  hipMemsetAsync(h_hi0, 0, (size_t)4 << 20, stream);
  hipMemsetAsync(cnt, 0, 128 * 16 * sizeof(unsigned int), stream);
  hipMemsetAsync(out_x, 0, (size_t)T_UNOBS_C * BATCH_C * 4 * sizeof(float), stream);

  prep_kernel<<<768, 256, 0, stream>>>(wi, w2, b2, bi,
                                       wi_hi, wi_lo, wh, wh_hi, wh_lo,
                                       wc_hi, wc_lo, bc_obs);

  void* args[] = {
    (void*)&x_obs, (void*)&t_obs, (void*)&w1, (void*)&b1,
    (void*)&wc_hi, (void*)&wc_lo, (void*)&wi_hi, (void*)&wi_lo,
    (void*)&wh_hi, (void*)&wh_lo,
    (void*)&bc_obs, (void*)&bi, (void*)&bh, (void*)&hw, (void*)&hb,
    (void*)&h_hi0, (void*)&h_lo0, (void*)&h_hi1, (void*)&h_lo1,
    (void*)&cnt, (void*)&out_x, (void*)&out_z
  };
  hipLaunchCooperativeKernel(reinterpret_cast<void*>(rnn_wave),
                             dim3(256), dim3(512), args, 0, stream);
}